// Round 1
// baseline (768.101 us; speedup 1.0000x reference)
//
#include <hip/hip_runtime.h>

#define NEG_SLOPE 0.2f

__device__ __forceinline__ float eluf(float x) { return x > 0.f ? x : __expf(x) - 1.f; }

// ---------------- CSR build ----------------

__global__ __launch_bounds__(256) void k_init(int* __restrict__ deg, int* __restrict__ flag, int N) {
  int i = blockIdx.x * 256 + threadIdx.x;
  if (i < N) deg[i] = 1;  // self-loop
  if (i == 0) *flag = 0;
}

// If edge_index arrived as int64, every odd int32 word is 0 (values < 2^31).
__global__ __launch_bounds__(256) void k_detect(const int* __restrict__ raw, int* __restrict__ flag, int nCheck) {
  int i = blockIdx.x * 256 + threadIdx.x;
  if (i < nCheck && raw[2 * i + 1] != 0) atomicOr(flag, 1);
}

__global__ __launch_bounds__(256) void k_convert(const int* __restrict__ raw, const int* __restrict__ flag,
                                                 int* __restrict__ out, int n) {
  int i = blockIdx.x * 256 + threadIdx.x;
  if (i >= n) return;
  bool is32 = (*flag != 0);
  out[i] = is32 ? raw[i] : raw[2 * i];
}

__global__ __launch_bounds__(256) void k_count(const int* __restrict__ ei, int* __restrict__ deg, int E) {
  int e = blockIdx.x * 256 + threadIdx.x;
  if (e < E) atomicAdd(&deg[ei[E + e]], 1);
}

__global__ __launch_bounds__(256) void k_blocksum(const int* __restrict__ deg, int* __restrict__ bsum, int N) {
  __shared__ int s[256];
  int t = threadIdx.x;
  int i = blockIdx.x * 256 + t;
  s[t] = (i < N) ? deg[i] : 0;
  __syncthreads();
  for (int off = 128; off > 0; off >>= 1) {
    if (t < off) s[t] += s[t + off];
    __syncthreads();
  }
  if (t == 0) bsum[blockIdx.x] = s[0];
}

__global__ __launch_bounds__(512) void k_scan_bsum(const int* __restrict__ bsum, int* __restrict__ boff,
                                                   int nb, int* __restrict__ rowptr, int N) {
  __shared__ int s[512];
  int t = threadIdx.x;
  int v = (t < nb) ? bsum[t] : 0;
  s[t] = v;
  __syncthreads();
  for (int off = 1; off < 512; off <<= 1) {
    int u = (t >= off) ? s[t - off] : 0;
    __syncthreads();
    s[t] += u;
    __syncthreads();
  }
  if (t < nb) boff[t] = s[t] - v;       // exclusive
  if (t == nb - 1) rowptr[N] = s[t];    // total = E + N
}

__global__ __launch_bounds__(256) void k_scan_final(const int* __restrict__ deg, const int* __restrict__ boff,
                                                    int* __restrict__ rowptr, int* __restrict__ cursor, int N) {
  __shared__ int s[256];
  int t = threadIdx.x;
  int i = blockIdx.x * 256 + t;
  int v = (i < N) ? deg[i] : 0;
  s[t] = v;
  __syncthreads();
  for (int off = 1; off < 256; off <<= 1) {
    int u = (t >= off) ? s[t - off] : 0;
    __syncthreads();
    s[t] += u;
    __syncthreads();
  }
  if (i < N) {
    int ex = boff[blockIdx.x] + s[t] - v;
    rowptr[i] = ex;
    cursor[i] = ex;
  }
}

__global__ __launch_bounds__(256) void k_fill(const int* __restrict__ ei, int* __restrict__ cursor,
                                              int* __restrict__ csr, int E, int N) {
  int idx = blockIdx.x * 256 + threadIdx.x;
  if (idx >= E + N) return;
  int s, d;
  if (idx < E) { s = ei[idx]; d = ei[E + idx]; }
  else         { s = d = idx - E; }
  int pos = atomicAdd(&cursor[d], 1);
  csr[pos] = s;
}

// ---------------- dense kernels ----------------

// Wt[k][c] = W[c][k], zero-padded to Kpad rows and 64 cols.
__global__ __launch_bounds__(256) void k_transpose_w(const float* __restrict__ W, float* __restrict__ Wt,
                                                     int OUTC, int K, int Kpad) {
  int idx = blockIdx.x * 256 + threadIdx.x;
  int k = idx >> 6, c = idx & 63;
  if (k < Kpad) Wt[k * 64 + c] = (k < K && c < OUTC) ? W[(size_t)c * K + k] : 0.f;
}

// C[M x OUTN] = X[M x K(ldx)] * Wt[K x 64], BM=128, BN=64, BK=32, 256 thr, 8x4 micro-tile.
// ELU_IN: X element -> elu(x + bias[k]) on load (fuses layer-1 bias+ELU into layer-2 GEMM).
template <bool ELU_IN>
__global__ __launch_bounds__(256) void k_gemm(const float* __restrict__ X, const float* __restrict__ Wt,
                                              const float* __restrict__ bias, float* __restrict__ out,
                                              int M, int K, int ldx, int OUTN, int ksteps) {
  __shared__ __align__(16) float xs[32][132];  // transposed x tile, padded (stride 132 -> 16B aligned, bank-safe)
  __shared__ __align__(16) float ws[32][64];
  const int t = threadIdx.x;
  const int rowg = t >> 4, colg = t & 15;
  const int brow = blockIdx.x * 128;
  float acc[8][4] = {};

  for (int ks = 0; ks < ksteps; ++ks) {
    const int k0 = ks * 32;
#pragma unroll
    for (int i = 0; i < 4; ++i) {
      int f = t + i * 256;            // 0..1023 : 128 rows x 8 float4
      int r = f >> 3, kq = f & 7;
      int grow = brow + r, gk = k0 + kq * 4;
      float4 v = {0.f, 0.f, 0.f, 0.f};
      if (grow < M && gk < K) {
        v = *reinterpret_cast<const float4*>(X + (size_t)grow * ldx + gk);
        if (ELU_IN) {
          v.x = eluf(v.x + bias[gk + 0]);
          v.y = eluf(v.y + bias[gk + 1]);
          v.z = eluf(v.z + bias[gk + 2]);
          v.w = eluf(v.w + bias[gk + 3]);
        }
      }
      xs[kq * 4 + 0][r] = v.x;
      xs[kq * 4 + 1][r] = v.y;
      xs[kq * 4 + 2][r] = v.z;
      xs[kq * 4 + 3][r] = v.w;
    }
#pragma unroll
    for (int i = 0; i < 2; ++i) {
      int f = t + i * 256;            // 0..511 : 32 k x 16 float4
      int kk = f >> 4, c4 = (f & 15) * 4;
      *reinterpret_cast<float4*>(&ws[kk][c4]) =
          *reinterpret_cast<const float4*>(Wt + (size_t)(k0 + kk) * 64 + c4);
    }
    __syncthreads();
#pragma unroll
    for (int k = 0; k < 32; ++k) {
      float4 xa = *reinterpret_cast<const float4*>(&xs[k][rowg * 8]);
      float4 xb = *reinterpret_cast<const float4*>(&xs[k][rowg * 8 + 4]);
      float4 wv = *reinterpret_cast<const float4*>(&ws[k][colg * 4]);
      float xr[8] = {xa.x, xa.y, xa.z, xa.w, xb.x, xb.y, xb.z, xb.w};
      float wc[4] = {wv.x, wv.y, wv.z, wv.w};
#pragma unroll
      for (int r = 0; r < 8; ++r)
#pragma unroll
        for (int c = 0; c < 4; ++c) acc[r][c] = fmaf(xr[r], wc[c], acc[r][c]);
    }
    __syncthreads();
  }

#pragma unroll
  for (int r = 0; r < 8; ++r) {
    int grow = brow + rowg * 8 + r;
    if (grow >= M) continue;
#pragma unroll
    for (int c = 0; c < 4; ++c) {
      int col = colg * 4 + c;
      if (col < OUTN) out[(size_t)grow * OUTN + col] = acc[r][c];
    }
  }
}

// alpha_s / alpha_d: per (node, head) dot of h[node, head*D..] with att vectors.
template <int D, int F>
__global__ __launch_bounds__(256) void k_alpha(const float* __restrict__ h, const float* __restrict__ a_src,
                                               const float* __restrict__ a_dst, float* __restrict__ as_,
                                               float* __restrict__ ad_, int N) {
  int idx = blockIdx.x * 256 + threadIdx.x;
  int node = idx >> 3, head = idx & 7;
  if (node >= N) return;
  const float* hr = h + (size_t)node * F + head * D;
  float ss = 0.f, sd = 0.f;
#pragma unroll
  for (int d = 0; d < D; ++d) {
    float v = hr[d];
    ss = fmaf(v, a_src[head * D + d], ss);
    sd = fmaf(v, a_dst[head * D + d], sd);
  }
  as_[idx] = ss;
  ad_[idx] = sd;
}

// One wave per dst node: online softmax over incoming edges, lane = output feature.
template <int D, int F>
__global__ __launch_bounds__(256) void k_agg(const float* __restrict__ h, const float* __restrict__ as_,
                                             const float* __restrict__ ad_, const int* __restrict__ rowptr,
                                             const int* __restrict__ csr, const float* __restrict__ bias,
                                             float* __restrict__ out, int N) {
  int lane = threadIdx.x & 63;
  int n = blockIdx.x * 4 + (threadIdx.x >> 6);
  if (n >= N) return;
  int head = (lane < F) ? (lane / D) : 0;
  int fidx = (lane < F) ? lane : 0;
  float ad_n = ad_[(size_t)n * 8 + head];
  int r0 = rowptr[n], r1 = rowptr[n + 1];
  float m = -1e30f, den = 0.f, acc = 0.f;
  for (int j = r0; j < r1; ++j) {
    int s = csr[j];
    float e = as_[(size_t)s * 8 + head] + ad_n;
    e = (e > 0.f) ? e : NEG_SLOPE * e;
    float nm = fmaxf(m, e);
    float sc = __expf(m - nm);
    float p = __expf(e - nm);
    float hv = h[(size_t)s * F + fidx];
    den = den * sc + p;
    acc = acc * sc + p * hv;
    m = nm;
  }
  if (lane < F) out[(size_t)n * F + lane] = acc / den + (bias ? bias[lane] : 0.f);
}

// ---------------- launch ----------------

extern "C" void kernel_launch(void* const* d_in, const int* in_sizes, int n_in,
                              void* d_out, int out_size, void* d_ws, size_t ws_size,
                              hipStream_t stream) {
  const float* x    = (const float*)d_in[0];
  const int*   ei   = (const int*)d_in[1];
  const float* W1   = (const float*)d_in[2];
  const float* at_s1 = (const float*)d_in[3];
  const float* at_d1 = (const float*)d_in[4];
  const float* b1   = (const float*)d_in[5];
  const float* W2   = (const float*)d_in[6];
  const float* at_s2 = (const float*)d_in[7];
  const float* at_d2 = (const float*)d_in[8];
  const float* b2   = (const float*)d_in[9];
  float* out = (float*)d_out;

  const int N = in_sizes[0] / 500;
  const int E = in_sizes[1] / 2;

  char* w = (char*)d_ws;
  auto alloc = [&](size_t bytes) -> void* {
    void* p = (void*)w;
    w += (bytes + 255) & ~(size_t)255;
    return p;
  };
  int*   rowptr = (int*)alloc((size_t)(N + 1) * 4);
  int*   cursor = (int*)alloc((size_t)N * 4);
  int*   deg    = (int*)alloc((size_t)N * 4);
  int*   flag   = (int*)alloc(256);
  int*   bsum   = (int*)alloc(4096);
  int*   boff   = (int*)alloc(4096);
  int*   ei_c   = (int*)alloc((size_t)2 * E * 4);
  int*   csr    = (int*)alloc((size_t)(E + N) * 4);
  float* h1     = (float*)alloc((size_t)N * 64 * 4);  // layer-1 h; later reused for layer-2 lin output [N,56]
  float* o1     = (float*)alloc((size_t)N * 64 * 4);  // layer-1 aggregated output
  float* asb    = (float*)alloc((size_t)N * 8 * 4);
  float* adb    = (float*)alloc((size_t)N * 8 * 4);
  float* Wt1    = (float*)alloc((size_t)512 * 64 * 4);
  float* Wt2    = (float*)alloc((size_t)64 * 64 * 4);

  auto cdiv = [](int a, int b) { return (a + b - 1) / b; };
  const int nbN = cdiv(N, 256);

  // CSR build (shared by both layers: same graph + self-loops)
  k_init<<<nbN, 256, 0, stream>>>(deg, flag, N);
  k_detect<<<cdiv(50000, 256), 256, 0, stream>>>(ei, flag, 50000);
  k_convert<<<cdiv(2 * E, 256), 256, 0, stream>>>(ei, flag, ei_c, 2 * E);
  k_count<<<cdiv(E, 256), 256, 0, stream>>>(ei_c, deg, E);
  k_blocksum<<<nbN, 256, 0, stream>>>(deg, bsum, N);
  k_scan_bsum<<<1, 512, 0, stream>>>(bsum, boff, nbN, rowptr, N);
  k_scan_final<<<nbN, 256, 0, stream>>>(deg, boff, rowptr, cursor, N);
  k_fill<<<cdiv(E + N, 256), 256, 0, stream>>>(ei_c, cursor, csr, E, N);

  // Layer 1
  k_transpose_w<<<cdiv(512 * 64, 256), 256, 0, stream>>>(W1, Wt1, 64, 500, 512);
  k_gemm<false><<<cdiv(N, 128), 256, 0, stream>>>(x, Wt1, nullptr, h1, N, 500, 500, 64, 16);
  k_alpha<8, 64><<<cdiv(N * 8, 256), 256, 0, stream>>>(h1, at_s1, at_d1, asb, adb, N);
  k_agg<8, 64><<<cdiv(N, 4), 256, 0, stream>>>(h1, asb, adb, rowptr, csr, nullptr, o1, N);

  // Layer 2 (bias b1 + ELU fused into GEMM2 input load)
  k_transpose_w<<<cdiv(64 * 64, 256), 256, 0, stream>>>(W2, Wt2, 56, 64, 64);
  k_gemm<true><<<cdiv(N, 128), 256, 0, stream>>>(o1, Wt2, b1, h1, N, 64, 64, 56, 2);
  k_alpha<7, 56><<<cdiv(N * 8, 256), 256, 0, stream>>>(h1, at_s2, at_d2, asb, adb, N);
  k_agg<7, 56><<<cdiv(N, 4), 256, 0, stream>>>(h1, asb, adb, rowptr, csr, b2, out, N);
}

// Round 2
// 628.033 us; speedup vs baseline: 1.2230x; 1.2230x over previous
//
#include <hip/hip_runtime.h>

#define NEG_SLOPE 0.2f

__device__ __forceinline__ float eluf(float x) { return x > 0.f ? x : __expf(x) - 1.f; }
__device__ __forceinline__ float lreluf(float x) { return x > 0.f ? x : NEG_SLOPE * x; }

// ---------------- CSR build ----------------

__global__ __launch_bounds__(256) void k_init(int* __restrict__ deg, int* __restrict__ flag, int N) {
  int i = blockIdx.x * 256 + threadIdx.x;
  if (i < N) deg[i] = 1;  // self-loop
  if (i == 0) *flag = 0;
}

// If edge_index arrived as int64, every odd int32 word is 0 (values < 2^31).
__global__ __launch_bounds__(256) void k_detect(const int* __restrict__ raw, int* __restrict__ flag, int nCheck) {
  int i = blockIdx.x * 256 + threadIdx.x;
  if (i < nCheck && raw[2 * i + 1] != 0) atomicOr(flag, 1);
}

__global__ __launch_bounds__(256) void k_convert(const int* __restrict__ raw, const int* __restrict__ flag,
                                                 int* __restrict__ out, int n) {
  int i = blockIdx.x * 256 + threadIdx.x;
  if (i >= n) return;
  bool is32 = (*flag != 0);
  out[i] = is32 ? raw[i] : raw[2 * i];
}

__global__ __launch_bounds__(256) void k_count(const int* __restrict__ ei, int* __restrict__ deg, int E) {
  int e = blockIdx.x * 256 + threadIdx.x;
  if (e < E) atomicAdd(&deg[ei[E + e]], 1);
}

__global__ __launch_bounds__(256) void k_blocksum(const int* __restrict__ deg, int* __restrict__ bsum, int N) {
  __shared__ int s[256];
  int t = threadIdx.x;
  int i = blockIdx.x * 256 + t;
  s[t] = (i < N) ? deg[i] : 0;
  __syncthreads();
  for (int off = 128; off > 0; off >>= 1) {
    if (t < off) s[t] += s[t + off];
    __syncthreads();
  }
  if (t == 0) bsum[blockIdx.x] = s[0];
}

__global__ __launch_bounds__(512) void k_scan_bsum(const int* __restrict__ bsum, int* __restrict__ boff,
                                                   int nb, int* __restrict__ rowptr, int N) {
  __shared__ int s[512];
  int t = threadIdx.x;
  int v = (t < nb) ? bsum[t] : 0;
  s[t] = v;
  __syncthreads();
  for (int off = 1; off < 512; off <<= 1) {
    int u = (t >= off) ? s[t - off] : 0;
    __syncthreads();
    s[t] += u;
    __syncthreads();
  }
  if (t < nb) boff[t] = s[t] - v;       // exclusive
  if (t == nb - 1) rowptr[N] = s[t];    // total = E + N
}

__global__ __launch_bounds__(256) void k_scan_final(const int* __restrict__ deg, const int* __restrict__ boff,
                                                    int* __restrict__ rowptr, int* __restrict__ cursor, int N) {
  __shared__ int s[256];
  int t = threadIdx.x;
  int i = blockIdx.x * 256 + t;
  int v = (i < N) ? deg[i] : 0;
  s[t] = v;
  __syncthreads();
  for (int off = 1; off < 256; off <<= 1) {
    int u = (t >= off) ? s[t - off] : 0;
    __syncthreads();
    s[t] += u;
    __syncthreads();
  }
  if (i < N) {
    int ex = boff[blockIdx.x] + s[t] - v;
    rowptr[i] = ex;
    cursor[i] = ex;
  }
}

__global__ __launch_bounds__(256) void k_fill(const int* __restrict__ ei, int* __restrict__ cursor,
                                              int* __restrict__ csr, int E, int N) {
  int idx = blockIdx.x * 256 + threadIdx.x;
  if (idx >= E + N) return;
  int s, d;
  if (idx < E) { s = ei[idx]; d = ei[E + idx]; }
  else         { s = d = idx - E; }
  int pos = atomicAdd(&cursor[d], 1);
  csr[pos] = s;
}

// ---------------- dense kernels ----------------

// Wt[k][c] = W[c][k], zero-padded to Kpad rows and 64 cols.
__global__ __launch_bounds__(256) void k_transpose_w(const float* __restrict__ W, float* __restrict__ Wt,
                                                     int OUTC, int K, int Kpad) {
  int idx = blockIdx.x * 256 + threadIdx.x;
  int k = idx >> 6, c = idx & 63;
  if (k < Kpad) Wt[k * 64 + c] = (k < K && c < OUTC) ? W[(size_t)c * K + k] : 0.f;
}

// C[M x OUTN] = X[M x K(ldx)] * Wt[K x 64], BM=128, BN=64, BK=32, 256 thr, 8x4 micro-tile.
// ELU_IN: X element -> elu(x + bias[k]) on load (fuses layer-1 bias+ELU into layer-2 GEMM).
template <bool ELU_IN>
__global__ __launch_bounds__(256) void k_gemm(const float* __restrict__ X, const float* __restrict__ Wt,
                                              const float* __restrict__ bias, float* __restrict__ out,
                                              int M, int K, int ldx, int OUTN, int ksteps) {
  __shared__ __align__(16) float xs[32][132];  // transposed x tile, padded
  __shared__ __align__(16) float ws[32][64];
  const int t = threadIdx.x;
  const int rowg = t >> 4, colg = t & 15;
  const int brow = blockIdx.x * 128;
  float acc[8][4] = {};

  for (int ks = 0; ks < ksteps; ++ks) {
    const int k0 = ks * 32;
#pragma unroll
    for (int i = 0; i < 4; ++i) {
      int f = t + i * 256;            // 0..1023 : 128 rows x 8 float4
      int r = f >> 3, kq = f & 7;
      int grow = brow + r, gk = k0 + kq * 4;
      float4 v = {0.f, 0.f, 0.f, 0.f};
      if (grow < M && gk < K) {
        v = *reinterpret_cast<const float4*>(X + (size_t)grow * ldx + gk);
        if (ELU_IN) {
          v.x = eluf(v.x + bias[gk + 0]);
          v.y = eluf(v.y + bias[gk + 1]);
          v.z = eluf(v.z + bias[gk + 2]);
          v.w = eluf(v.w + bias[gk + 3]);
        }
      }
      xs[kq * 4 + 0][r] = v.x;
      xs[kq * 4 + 1][r] = v.y;
      xs[kq * 4 + 2][r] = v.z;
      xs[kq * 4 + 3][r] = v.w;
    }
#pragma unroll
    for (int i = 0; i < 2; ++i) {
      int f = t + i * 256;            // 0..511 : 32 k x 16 float4
      int kk = f >> 4, c4 = (f & 15) * 4;
      *reinterpret_cast<float4*>(&ws[kk][c4]) =
          *reinterpret_cast<const float4*>(Wt + (size_t)(k0 + kk) * 64 + c4);
    }
    __syncthreads();
#pragma unroll
    for (int k = 0; k < 32; ++k) {
      float4 xa = *reinterpret_cast<const float4*>(&xs[k][rowg * 8]);
      float4 xb = *reinterpret_cast<const float4*>(&xs[k][rowg * 8 + 4]);
      float4 wv = *reinterpret_cast<const float4*>(&ws[k][colg * 4]);
      float xr[8] = {xa.x, xa.y, xa.z, xa.w, xb.x, xb.y, xb.z, xb.w};
      float wc[4] = {wv.x, wv.y, wv.z, wv.w};
#pragma unroll
      for (int r = 0; r < 8; ++r)
#pragma unroll
        for (int c = 0; c < 4; ++c) acc[r][c] = fmaf(xr[r], wc[c], acc[r][c]);
    }
    __syncthreads();
  }

#pragma unroll
  for (int r = 0; r < 8; ++r) {
    int grow = brow + rowg * 8 + r;
    if (grow >= M) continue;
#pragma unroll
    for (int c = 0; c < 4; ++c) {
      int col = colg * 4 + c;
      if (col < OUTN) out[(size_t)grow * OUTN + col] = acc[r][c];
    }
  }
}

// alpha_s / alpha_d: per (node, head) dot of h[node, head*D..] with att vectors.
template <int D, int F>
__global__ __launch_bounds__(256) void k_alpha(const float* __restrict__ h, const float* __restrict__ a_src,
                                               const float* __restrict__ a_dst, float* __restrict__ as_,
                                               float* __restrict__ ad_, int N) {
  int idx = blockIdx.x * 256 + threadIdx.x;
  int node = idx >> 3, head = idx & 7;
  if (node >= N) return;
  const float* hr = h + (size_t)node * F + head * D;
  float ss = 0.f, sd = 0.f;
#pragma unroll
  for (int d = 0; d < D; ++d) {
    float v = hr[d];
    ss = fmaf(v, a_src[head * D + d], ss);
    sd = fmaf(v, a_dst[head * D + d], sd);
  }
  as_[idx] = ss;
  ad_[idx] = sd;
}

// One wave per dst node, two-pass softmax aggregation.
// Pass 1: lane l handles head (l&7), edges r0+(l>>3)+8k -> 8 edges/iter; butterfly combine.
// Pass 2: exact m/den known -> unordered sum, unroll x4 with independent accumulators (4x MLP).
template <int D, int F>
__global__ __launch_bounds__(256) void k_agg(const float* __restrict__ h, const float* __restrict__ as_,
                                             const float* __restrict__ ad_, const int* __restrict__ rowptr,
                                             const int* __restrict__ csr, const float* __restrict__ bias,
                                             float* __restrict__ out, int N) {
  const int lane = threadIdx.x & 63;
  const int n = blockIdx.x * 4 + (threadIdx.x >> 6);
  if (n >= N) return;
  const int r0 = rowptr[n], r1 = rowptr[n + 1];

  // ---- pass 1: per-(node,head) max & denom
  const int h1_ = lane & 7;
  const float ad_h = ad_[(size_t)n * 8 + h1_];
  float m = -1e30f, den = 0.f;
  for (int j = r0 + (lane >> 3); j < r1; j += 8) {
    int s = csr[j];
    float e = lreluf(as_[(size_t)s * 8 + h1_] + ad_h);
    float nm = fmaxf(m, e);
    den = den * __expf(m - nm) + __expf(e - nm);
    m = nm;
  }
#pragma unroll
  for (int off = 8; off < 64; off <<= 1) {
    float mo = __shfl_xor(m, off);
    float dn = __shfl_xor(den, off);
    float nm = fmaxf(m, mo);
    den = den * __expf(m - nm) + dn * __expf(mo - nm);
    m = nm;
  }
  // lane l now holds exact (m, den) for head (l&7)

  // ---- pass 2: lane = output feature
  const int head = (lane < F) ? (lane / D) : 0;
  const int fidx = (lane < F) ? lane : 0;
  const float m_h = __shfl(m, head);
  const float inv_den = 1.f / __shfl(den, head);
  const float ad_n = __shfl(ad_h, head);  // lane 'head' holds ad_[n*8+head]

  float acc0 = 0.f, acc1 = 0.f, acc2 = 0.f, acc3 = 0.f;
  int j = r0;
  for (; j + 3 < r1; j += 4) {
    int s0 = csr[j + 0], s1 = csr[j + 1], s2 = csr[j + 2], s3 = csr[j + 3];
    float a0 = as_[(size_t)s0 * 8 + head];
    float a1 = as_[(size_t)s1 * 8 + head];
    float a2 = as_[(size_t)s2 * 8 + head];
    float a3 = as_[(size_t)s3 * 8 + head];
    float v0 = h[(size_t)s0 * F + fidx];
    float v1 = h[(size_t)s1 * F + fidx];
    float v2 = h[(size_t)s2 * F + fidx];
    float v3 = h[(size_t)s3 * F + fidx];
    acc0 = fmaf(__expf(lreluf(a0 + ad_n) - m_h), v0, acc0);
    acc1 = fmaf(__expf(lreluf(a1 + ad_n) - m_h), v1, acc1);
    acc2 = fmaf(__expf(lreluf(a2 + ad_n) - m_h), v2, acc2);
    acc3 = fmaf(__expf(lreluf(a3 + ad_n) - m_h), v3, acc3);
  }
  for (; j < r1; ++j) {
    int s = csr[j];
    float a = as_[(size_t)s * 8 + head];
    float v = h[(size_t)s * F + fidx];
    acc0 = fmaf(__expf(lreluf(a + ad_n) - m_h), v, acc0);
  }
  if (lane < F)
    out[(size_t)n * F + lane] = (acc0 + acc1 + acc2 + acc3) * inv_den + (bias ? bias[lane] : 0.f);
}

// ---------------- launch ----------------

extern "C" void kernel_launch(void* const* d_in, const int* in_sizes, int n_in,
                              void* d_out, int out_size, void* d_ws, size_t ws_size,
                              hipStream_t stream) {
  const float* x    = (const float*)d_in[0];
  const int*   ei   = (const int*)d_in[1];
  const float* W1   = (const float*)d_in[2];
  const float* at_s1 = (const float*)d_in[3];
  const float* at_d1 = (const float*)d_in[4];
  const float* b1   = (const float*)d_in[5];
  const float* W2   = (const float*)d_in[6];
  const float* at_s2 = (const float*)d_in[7];
  const float* at_d2 = (const float*)d_in[8];
  const float* b2   = (const float*)d_in[9];
  float* out = (float*)d_out;

  const int N = in_sizes[0] / 500;
  const int E = in_sizes[1] / 2;

  char* w = (char*)d_ws;
  auto alloc = [&](size_t bytes) -> void* {
    void* p = (void*)w;
    w += (bytes + 255) & ~(size_t)255;
    return p;
  };
  int*   rowptr = (int*)alloc((size_t)(N + 1) * 4);
  int*   cursor = (int*)alloc((size_t)N * 4);
  int*   deg    = (int*)alloc((size_t)N * 4);
  int*   flag   = (int*)alloc(256);
  int*   bsum   = (int*)alloc(4096);
  int*   boff   = (int*)alloc(4096);
  int*   ei_c   = (int*)alloc((size_t)2 * E * 4);
  int*   csr    = (int*)alloc((size_t)(E + N) * 4);
  float* h1     = (float*)alloc((size_t)N * 64 * 4);  // layer-1 h; later reused for layer-2 lin output [N,56]
  float* o1     = (float*)alloc((size_t)N * 64 * 4);  // layer-1 aggregated output
  float* asb    = (float*)alloc((size_t)N * 8 * 4);
  float* adb    = (float*)alloc((size_t)N * 8 * 4);
  float* Wt1    = (float*)alloc((size_t)512 * 64 * 4);
  float* Wt2    = (float*)alloc((size_t)64 * 64 * 4);

  auto cdiv = [](int a, int b) { return (a + b - 1) / b; };
  const int nbN = cdiv(N, 256);

  // CSR build (shared by both layers: same graph + self-loops)
  k_init<<<nbN, 256, 0, stream>>>(deg, flag, N);
  k_detect<<<cdiv(50000, 256), 256, 0, stream>>>(ei, flag, 50000);
  k_convert<<<cdiv(2 * E, 256), 256, 0, stream>>>(ei, flag, ei_c, 2 * E);
  k_count<<<cdiv(E, 256), 256, 0, stream>>>(ei_c, deg, E);
  k_blocksum<<<nbN, 256, 0, stream>>>(deg, bsum, N);
  k_scan_bsum<<<1, 512, 0, stream>>>(bsum, boff, nbN, rowptr, N);
  k_scan_final<<<nbN, 256, 0, stream>>>(deg, boff, rowptr, cursor, N);
  k_fill<<<cdiv(E + N, 256), 256, 0, stream>>>(ei_c, cursor, csr, E, N);

  // Layer 1
  k_transpose_w<<<cdiv(512 * 64, 256), 256, 0, stream>>>(W1, Wt1, 64, 500, 512);
  k_gemm<false><<<cdiv(N, 128), 256, 0, stream>>>(x, Wt1, nullptr, h1, N, 500, 500, 64, 16);
  k_alpha<8, 64><<<cdiv(N * 8, 256), 256, 0, stream>>>(h1, at_s1, at_d1, asb, adb, N);
  k_agg<8, 64><<<cdiv(N, 4), 256, 0, stream>>>(h1, asb, adb, rowptr, csr, nullptr, o1, N);

  // Layer 2 (bias b1 + ELU fused into GEMM2 input load)
  k_transpose_w<<<cdiv(64 * 64, 256), 256, 0, stream>>>(W2, Wt2, 56, 64, 64);
  k_gemm<true><<<cdiv(N, 128), 256, 0, stream>>>(o1, Wt2, b1, h1, N, 64, 64, 56, 2);
  k_alpha<7, 56><<<cdiv(N * 8, 256), 256, 0, stream>>>(h1, at_s2, at_d2, asb, adb, N);
  k_agg<7, 56><<<cdiv(N, 4), 256, 0, stream>>>(h1, asb, adb, rowptr, csr, b2, out, N);
}

// Round 3
// 563.849 us; speedup vs baseline: 1.3622x; 1.1138x over previous
//
#include <hip/hip_runtime.h>

#define NEG_SLOPE 0.2f

typedef __bf16 bf16x8 __attribute__((ext_vector_type(8)));
typedef float f32x4 __attribute__((ext_vector_type(4)));

__device__ __forceinline__ float eluf(float x) { return x > 0.f ? x : __expf(x) - 1.f; }
__device__ __forceinline__ float lreluf(float x) { return x > 0.f ? x : NEG_SLOPE * x; }

// ---------------- CSR build ----------------

__global__ __launch_bounds__(256) void k_init(int* __restrict__ deg, int* __restrict__ flag, int N) {
  int i = blockIdx.x * 256 + threadIdx.x;
  if (i < N) deg[i] = 1;  // self-loop
  if (i == 0) *flag = 0;
}

// If edge_index arrived as int64, every odd int32 word is 0 (values < 2^31).
__global__ __launch_bounds__(256) void k_detect(const int* __restrict__ raw, int* __restrict__ flag, int nCheck) {
  int i = blockIdx.x * 256 + threadIdx.x;
  if (i < nCheck && raw[2 * i + 1] != 0) atomicOr(flag, 1);
}

__global__ __launch_bounds__(256) void k_convert(const int* __restrict__ raw, const int* __restrict__ flag,
                                                 int* __restrict__ out, int n) {
  int i = blockIdx.x * 256 + threadIdx.x;
  if (i >= n) return;
  bool is32 = (*flag != 0);
  out[i] = is32 ? raw[i] : raw[2 * i];
}

__global__ __launch_bounds__(256) void k_count(const int* __restrict__ ei, int* __restrict__ deg, int E) {
  int e = blockIdx.x * 256 + threadIdx.x;
  if (e < E) atomicAdd(&deg[ei[E + e]], 1);
}

__global__ __launch_bounds__(256) void k_blocksum(const int* __restrict__ deg, int* __restrict__ bsum, int N) {
  __shared__ int s[256];
  int t = threadIdx.x;
  int i = blockIdx.x * 256 + t;
  s[t] = (i < N) ? deg[i] : 0;
  __syncthreads();
  for (int off = 128; off > 0; off >>= 1) {
    if (t < off) s[t] += s[t + off];
    __syncthreads();
  }
  if (t == 0) bsum[blockIdx.x] = s[0];
}

__global__ __launch_bounds__(512) void k_scan_bsum(const int* __restrict__ bsum, int* __restrict__ boff,
                                                   int nb, int* __restrict__ rowptr, int N) {
  __shared__ int s[512];
  int t = threadIdx.x;
  int v = (t < nb) ? bsum[t] : 0;
  s[t] = v;
  __syncthreads();
  for (int off = 1; off < 512; off <<= 1) {
    int u = (t >= off) ? s[t - off] : 0;
    __syncthreads();
    s[t] += u;
    __syncthreads();
  }
  if (t < nb) boff[t] = s[t] - v;       // exclusive
  if (t == nb - 1) rowptr[N] = s[t];    // total = E + N
}

__global__ __launch_bounds__(256) void k_scan_final(const int* __restrict__ deg, const int* __restrict__ boff,
                                                    int* __restrict__ rowptr, int* __restrict__ cursor, int N) {
  __shared__ int s[256];
  int t = threadIdx.x;
  int i = blockIdx.x * 256 + t;
  int v = (i < N) ? deg[i] : 0;
  s[t] = v;
  __syncthreads();
  for (int off = 1; off < 256; off <<= 1) {
    int u = (t >= off) ? s[t - off] : 0;
    __syncthreads();
    s[t] += u;
    __syncthreads();
  }
  if (i < N) {
    int ex = boff[blockIdx.x] + s[t] - v;
    rowptr[i] = ex;
    cursor[i] = ex;
  }
}

__global__ __launch_bounds__(256) void k_fill(const int* __restrict__ ei, int* __restrict__ cursor,
                                              int* __restrict__ csr, int E, int N) {
  int idx = blockIdx.x * 256 + threadIdx.x;
  if (idx >= E + N) return;
  int s, d;
  if (idx < E) { s = ei[idx]; d = ei[E + idx]; }
  else         { s = d = idx - E; }
  int pos = atomicAdd(&cursor[d], 1);
  csr[pos] = s;
}

// ---------------- layer-1 GEMM: split-bf16 MFMA ----------------

// Pack W1^T into per-lane MFMA B fragments (hi/lo split).
// Layout: frag idx = ((ks*4 + nf)*64 + lane), element e:
//   k = ks*32 + (lane>>4)*8 + e,  col = nf*16 + (lane&15),  value = W1[col][k] (0 if k>=500)
__global__ __launch_bounds__(256) void k_prep_b1(const float* __restrict__ W1, __bf16* __restrict__ bhi,
                                                 __bf16* __restrict__ blo) {
  int idx = blockIdx.x * 256 + threadIdx.x;  // 0 .. 16*4*64*8-1 = 32767
  if (idx >= 16 * 4 * 64 * 8) return;
  int e = idx & 7;
  int lane = (idx >> 3) & 63;
  int nf = (idx >> 9) & 3;
  int ks = idx >> 11;
  int k = ks * 32 + (lane >> 4) * 8 + e;
  int col = nf * 16 + (lane & 15);
  float w = (k < 500) ? W1[(size_t)col * 500 + k] : 0.f;
  __bf16 h = (__bf16)w;
  bhi[idx] = h;
  blo[idx] = (__bf16)(w - (float)h);
}

// C[M x 64] = X[M x 500] * W1^T, via 3-term split-bf16 MFMA (fp32-class accuracy).
// 4 waves/block, 16 rows/wave, no LDS. A loaded direct from global (rows 16B aligned).
__global__ __launch_bounds__(256) void k_gemm1_mfma(const float* __restrict__ X, const bf16x8* __restrict__ Bhi,
                                                    const bf16x8* __restrict__ Blo, float* __restrict__ out, int M) {
  const int lane = threadIdx.x & 63;
  const int wid = threadIdx.x >> 6;
  const int row0 = blockIdx.x * 64 + wid * 16;
  const int arow = row0 + (lane & 15);
  const int kgrp = lane >> 4;                 // 0..3
  const bool rowok = arow < M;
  const float* xrow = X + (size_t)arow * 500;

  f32x4 acc[4];
#pragma unroll
  for (int nf = 0; nf < 4; ++nf) acc[nf] = (f32x4){0.f, 0.f, 0.f, 0.f};

#pragma unroll
  for (int ks = 0; ks < 16; ++ks) {
    const int k0 = ks * 32 + kgrp * 8;
    float v[8];
    if (rowok && k0 + 7 < 500) {
      float4 p = *reinterpret_cast<const float4*>(xrow + k0);
      float4 q = *reinterpret_cast<const float4*>(xrow + k0 + 4);
      v[0] = p.x; v[1] = p.y; v[2] = p.z; v[3] = p.w;
      v[4] = q.x; v[5] = q.y; v[6] = q.z; v[7] = q.w;
    } else {
#pragma unroll
      for (int e = 0; e < 8; ++e) v[e] = (rowok && k0 + e < 500) ? xrow[k0 + e] : 0.f;
    }
    bf16x8 ahi, alo;
#pragma unroll
    for (int e = 0; e < 8; ++e) {
      __bf16 h = (__bf16)v[e];
      ahi[e] = h;
      alo[e] = (__bf16)(v[e] - (float)h);
    }
#pragma unroll
    for (int nf = 0; nf < 4; ++nf) {
      bf16x8 bh = Bhi[(ks * 4 + nf) * 64 + lane];
      bf16x8 bl = Blo[(ks * 4 + nf) * 64 + lane];
      acc[nf] = __builtin_amdgcn_mfma_f32_16x16x32_bf16(ahi, bh, acc[nf], 0, 0, 0);
      acc[nf] = __builtin_amdgcn_mfma_f32_16x16x32_bf16(alo, bh, acc[nf], 0, 0, 0);
      acc[nf] = __builtin_amdgcn_mfma_f32_16x16x32_bf16(ahi, bl, acc[nf], 0, 0, 0);
    }
  }

  // D: col = lane&15, row = (lane>>4)*4 + r
  const int col = lane & 15;
#pragma unroll
  for (int r = 0; r < 4; ++r) {
    int rowd = row0 + (lane >> 4) * 4 + r;
    if (rowd >= M) continue;
#pragma unroll
    for (int nf = 0; nf < 4; ++nf) out[(size_t)rowd * 64 + nf * 16 + col] = acc[nf][r];
  }
}

// ---------------- dense fp32 GEMM (layer 2) ----------------

// Wt[k][c] = W[c][k], zero-padded to Kpad rows and 64 cols.
__global__ __launch_bounds__(256) void k_transpose_w(const float* __restrict__ W, float* __restrict__ Wt,
                                                     int OUTC, int K, int Kpad) {
  int idx = blockIdx.x * 256 + threadIdx.x;
  int k = idx >> 6, c = idx & 63;
  if (k < Kpad) Wt[k * 64 + c] = (k < K && c < OUTC) ? W[(size_t)c * K + k] : 0.f;
}

template <bool ELU_IN>
__global__ __launch_bounds__(256) void k_gemm(const float* __restrict__ X, const float* __restrict__ Wt,
                                              const float* __restrict__ bias, float* __restrict__ out,
                                              int M, int K, int ldx, int OUTN, int ksteps) {
  __shared__ __align__(16) float xs[32][132];
  __shared__ __align__(16) float ws[32][64];
  const int t = threadIdx.x;
  const int rowg = t >> 4, colg = t & 15;
  const int brow = blockIdx.x * 128;
  float acc[8][4] = {};

  for (int ks = 0; ks < ksteps; ++ks) {
    const int k0 = ks * 32;
#pragma unroll
    for (int i = 0; i < 4; ++i) {
      int f = t + i * 256;
      int r = f >> 3, kq = f & 7;
      int grow = brow + r, gk = k0 + kq * 4;
      float4 v = {0.f, 0.f, 0.f, 0.f};
      if (grow < M && gk < K) {
        v = *reinterpret_cast<const float4*>(X + (size_t)grow * ldx + gk);
        if (ELU_IN) {
          v.x = eluf(v.x + bias[gk + 0]);
          v.y = eluf(v.y + bias[gk + 1]);
          v.z = eluf(v.z + bias[gk + 2]);
          v.w = eluf(v.w + bias[gk + 3]);
        }
      }
      xs[kq * 4 + 0][r] = v.x;
      xs[kq * 4 + 1][r] = v.y;
      xs[kq * 4 + 2][r] = v.z;
      xs[kq * 4 + 3][r] = v.w;
    }
#pragma unroll
    for (int i = 0; i < 2; ++i) {
      int f = t + i * 256;
      int kk = f >> 4, c4 = (f & 15) * 4;
      *reinterpret_cast<float4*>(&ws[kk][c4]) =
          *reinterpret_cast<const float4*>(Wt + (size_t)(k0 + kk) * 64 + c4);
    }
    __syncthreads();
#pragma unroll
    for (int k = 0; k < 32; ++k) {
      float4 xa = *reinterpret_cast<const float4*>(&xs[k][rowg * 8]);
      float4 xb = *reinterpret_cast<const float4*>(&xs[k][rowg * 8 + 4]);
      float4 wv = *reinterpret_cast<const float4*>(&ws[k][colg * 4]);
      float xr[8] = {xa.x, xa.y, xa.z, xa.w, xb.x, xb.y, xb.z, xb.w};
      float wc[4] = {wv.x, wv.y, wv.z, wv.w};
#pragma unroll
      for (int r = 0; r < 8; ++r)
#pragma unroll
        for (int c = 0; c < 4; ++c) acc[r][c] = fmaf(xr[r], wc[c], acc[r][c]);
    }
    __syncthreads();
  }

#pragma unroll
  for (int r = 0; r < 8; ++r) {
    int grow = brow + rowg * 8 + r;
    if (grow >= M) continue;
#pragma unroll
    for (int c = 0; c < 4; ++c) {
      int col = colg * 4 + c;
      if (col < OUTN) out[(size_t)grow * OUTN + col] = acc[r][c];
    }
  }
}

// alpha_s / alpha_d: per (node, head) dot of h[node, head*D..] with att vectors.
template <int D, int F>
__global__ __launch_bounds__(256) void k_alpha(const float* __restrict__ h, const float* __restrict__ a_src,
                                               const float* __restrict__ a_dst, float* __restrict__ as_,
                                               float* __restrict__ ad_, int N) {
  int idx = blockIdx.x * 256 + threadIdx.x;
  int node = idx >> 3, head = idx & 7;
  if (node >= N) return;
  const float* hr = h + (size_t)node * F + head * D;
  float ss = 0.f, sd = 0.f;
#pragma unroll
  for (int d = 0; d < D; ++d) {
    float v = hr[d];
    ss = fmaf(v, a_src[head * D + d], ss);
    sd = fmaf(v, a_dst[head * D + d], sd);
  }
  as_[idx] = ss;
  ad_[idx] = sd;
}

// One wave per dst node, two-pass softmax aggregation.
template <int D, int F>
__global__ __launch_bounds__(256) void k_agg(const float* __restrict__ h, const float* __restrict__ as_,
                                             const float* __restrict__ ad_, const int* __restrict__ rowptr,
                                             const int* __restrict__ csr, const float* __restrict__ bias,
                                             float* __restrict__ out, int N) {
  const int lane = threadIdx.x & 63;
  const int n = blockIdx.x * 4 + (threadIdx.x >> 6);
  if (n >= N) return;
  const int r0 = rowptr[n], r1 = rowptr[n + 1];

  // ---- pass 1: per-(node,head) max & denom
  const int h1_ = lane & 7;
  const float ad_h = ad_[(size_t)n * 8 + h1_];
  float m = -1e30f, den = 0.f;
  for (int j = r0 + (lane >> 3); j < r1; j += 8) {
    int s = csr[j];
    float e = lreluf(as_[(size_t)s * 8 + h1_] + ad_h);
    float nm = fmaxf(m, e);
    den = den * __expf(m - nm) + __expf(e - nm);
    m = nm;
  }
#pragma unroll
  for (int off = 8; off < 64; off <<= 1) {
    float mo = __shfl_xor(m, off);
    float dn = __shfl_xor(den, off);
    float nm = fmaxf(m, mo);
    den = den * __expf(m - nm) + dn * __expf(mo - nm);
    m = nm;
  }

  // ---- pass 2: lane = output feature
  const int head = (lane < F) ? (lane / D) : 0;
  const int fidx = (lane < F) ? lane : 0;
  const float m_h = __shfl(m, head);
  const float inv_den = 1.f / __shfl(den, head);
  const float ad_n = __shfl(ad_h, head);

  float acc0 = 0.f, acc1 = 0.f, acc2 = 0.f, acc3 = 0.f;
  int j = r0;
  for (; j + 3 < r1; j += 4) {
    int s0 = csr[j + 0], s1 = csr[j + 1], s2 = csr[j + 2], s3 = csr[j + 3];
    float a0 = as_[(size_t)s0 * 8 + head];
    float a1 = as_[(size_t)s1 * 8 + head];
    float a2 = as_[(size_t)s2 * 8 + head];
    float a3 = as_[(size_t)s3 * 8 + head];
    float v0 = h[(size_t)s0 * F + fidx];
    float v1 = h[(size_t)s1 * F + fidx];
    float v2 = h[(size_t)s2 * F + fidx];
    float v3 = h[(size_t)s3 * F + fidx];
    acc0 = fmaf(__expf(lreluf(a0 + ad_n) - m_h), v0, acc0);
    acc1 = fmaf(__expf(lreluf(a1 + ad_n) - m_h), v1, acc1);
    acc2 = fmaf(__expf(lreluf(a2 + ad_n) - m_h), v2, acc2);
    acc3 = fmaf(__expf(lreluf(a3 + ad_n) - m_h), v3, acc3);
  }
  for (; j < r1; ++j) {
    int s = csr[j];
    float a = as_[(size_t)s * 8 + head];
    float v = h[(size_t)s * F + fidx];
    acc0 = fmaf(__expf(lreluf(a + ad_n) - m_h), v, acc0);
  }
  if (lane < F)
    out[(size_t)n * F + lane] = (acc0 + acc1 + acc2 + acc3) * inv_den + (bias ? bias[lane] : 0.f);
}

// ---------------- launch ----------------

extern "C" void kernel_launch(void* const* d_in, const int* in_sizes, int n_in,
                              void* d_out, int out_size, void* d_ws, size_t ws_size,
                              hipStream_t stream) {
  const float* x    = (const float*)d_in[0];
  const int*   ei   = (const int*)d_in[1];
  const float* W1   = (const float*)d_in[2];
  const float* at_s1 = (const float*)d_in[3];
  const float* at_d1 = (const float*)d_in[4];
  const float* b1   = (const float*)d_in[5];
  const float* W2   = (const float*)d_in[6];
  const float* at_s2 = (const float*)d_in[7];
  const float* at_d2 = (const float*)d_in[8];
  const float* b2   = (const float*)d_in[9];
  float* out = (float*)d_out;

  const int N = in_sizes[0] / 500;
  const int E = in_sizes[1] / 2;

  char* w = (char*)d_ws;
  auto alloc = [&](size_t bytes) -> void* {
    void* p = (void*)w;
    w += (bytes + 255) & ~(size_t)255;
    return p;
  };
  int*   rowptr = (int*)alloc((size_t)(N + 1) * 4);
  int*   cursor = (int*)alloc((size_t)N * 4);
  int*   deg    = (int*)alloc((size_t)N * 4);
  int*   flag   = (int*)alloc(256);
  int*   bsum   = (int*)alloc(4096);
  int*   boff   = (int*)alloc(4096);
  int*   ei_c   = (int*)alloc((size_t)2 * E * 4);
  int*   csr    = (int*)alloc((size_t)(E + N) * 4);
  float* h1     = (float*)alloc((size_t)N * 64 * 4);
  float* o1     = (float*)alloc((size_t)N * 64 * 4);
  float* asb    = (float*)alloc((size_t)N * 8 * 4);
  float* adb    = (float*)alloc((size_t)N * 8 * 4);
  float* Wt2    = (float*)alloc((size_t)64 * 64 * 4);
  __bf16* Bhi1  = (__bf16*)alloc((size_t)32768 * 2);
  __bf16* Blo1  = (__bf16*)alloc((size_t)32768 * 2);

  auto cdiv = [](int a, int b) { return (a + b - 1) / b; };
  const int nbN = cdiv(N, 256);

  // CSR build (shared by both layers: same graph + self-loops)
  k_init<<<nbN, 256, 0, stream>>>(deg, flag, N);
  k_detect<<<cdiv(50000, 256), 256, 0, stream>>>(ei, flag, 50000);
  k_convert<<<cdiv(2 * E, 256), 256, 0, stream>>>(ei, flag, ei_c, 2 * E);
  k_count<<<cdiv(E, 256), 256, 0, stream>>>(ei_c, deg, E);
  k_blocksum<<<nbN, 256, 0, stream>>>(deg, bsum, N);
  k_scan_bsum<<<1, 512, 0, stream>>>(bsum, boff, nbN, rowptr, N);
  k_scan_final<<<nbN, 256, 0, stream>>>(deg, boff, rowptr, cursor, N);
  k_fill<<<cdiv(E + N, 256), 256, 0, stream>>>(ei_c, cursor, csr, E, N);

  // Layer 1 (split-bf16 MFMA GEMM)
  k_prep_b1<<<cdiv(32768, 256), 256, 0, stream>>>(W1, Bhi1, Blo1);
  k_gemm1_mfma<<<cdiv(N, 64), 256, 0, stream>>>(x, (const bf16x8*)Bhi1, (const bf16x8*)Blo1, h1, N);
  k_alpha<8, 64><<<cdiv(N * 8, 256), 256, 0, stream>>>(h1, at_s1, at_d1, asb, adb, N);
  k_agg<8, 64><<<cdiv(N, 4), 256, 0, stream>>>(h1, asb, adb, rowptr, csr, nullptr, o1, N);

  // Layer 2 (bias b1 + ELU fused into GEMM2 input load)
  k_transpose_w<<<cdiv(64 * 64, 256), 256, 0, stream>>>(W2, Wt2, 56, 64, 64);
  k_gemm<true><<<cdiv(N, 128), 256, 0, stream>>>(o1, Wt2, b1, h1, N, 64, 64, 56, 2);
  k_alpha<7, 56><<<cdiv(N * 8, 256), 256, 0, stream>>>(h1, at_s2, at_d2, asb, adb, N);
  k_agg<7, 56><<<cdiv(N, 4), 256, 0, stream>>>(h1, asb, adb, rowptr, csr, b2, out, N);
}

// Round 4
// 509.285 us; speedup vs baseline: 1.5082x; 1.1071x over previous
//
#include <hip/hip_runtime.h>

#define NEG_SLOPE 0.2f

typedef __bf16 bf16x8 __attribute__((ext_vector_type(8)));
typedef float f32x4 __attribute__((ext_vector_type(4)));

__device__ __forceinline__ float eluf(float x) { return x > 0.f ? x : __expf(x) - 1.f; }
__device__ __forceinline__ float lreluf(float x) { return x > 0.f ? x : NEG_SLOPE * x; }

// ---------------- CSR build ----------------

__global__ __launch_bounds__(256) void k_init(int* __restrict__ deg, int* __restrict__ flag, int N) {
  int i = blockIdx.x * 256 + threadIdx.x;
  if (i < N) deg[i] = 1;  // self-loop
  if (i == 0) *flag = 0;
}

// If edge_index arrived as int64, every odd int32 word is 0 (values < 2^31).
__global__ __launch_bounds__(256) void k_detect(const int* __restrict__ raw, int* __restrict__ flag, int nCheck) {
  int i = blockIdx.x * 256 + threadIdx.x;
  if (i < nCheck && raw[2 * i + 1] != 0) atomicOr(flag, 1);
}

__global__ __launch_bounds__(256) void k_convert(const int* __restrict__ raw, const int* __restrict__ flag,
                                                 int* __restrict__ out, int n) {
  int i = blockIdx.x * 256 + threadIdx.x;
  if (i >= n) return;
  bool is32 = (*flag != 0);
  out[i] = is32 ? raw[i] : raw[2 * i];
}

__global__ __launch_bounds__(256) void k_count(const int* __restrict__ ei, int* __restrict__ deg, int E) {
  int e = blockIdx.x * 256 + threadIdx.x;
  if (e < E) atomicAdd(&deg[ei[E + e]], 1);
}

__global__ __launch_bounds__(256) void k_blocksum(const int* __restrict__ deg, int* __restrict__ bsum, int N) {
  __shared__ int s[256];
  int t = threadIdx.x;
  int i = blockIdx.x * 256 + t;
  s[t] = (i < N) ? deg[i] : 0;
  __syncthreads();
  for (int off = 128; off > 0; off >>= 1) {
    if (t < off) s[t] += s[t + off];
    __syncthreads();
  }
  if (t == 0) bsum[blockIdx.x] = s[0];
}

__global__ __launch_bounds__(512) void k_scan_bsum(const int* __restrict__ bsum, int* __restrict__ boff,
                                                   int nb, int* __restrict__ rowptr, int N) {
  __shared__ int s[512];
  int t = threadIdx.x;
  int v = (t < nb) ? bsum[t] : 0;
  s[t] = v;
  __syncthreads();
  for (int off = 1; off < 512; off <<= 1) {
    int u = (t >= off) ? s[t - off] : 0;
    __syncthreads();
    s[t] += u;
    __syncthreads();
  }
  if (t < nb) boff[t] = s[t] - v;       // exclusive
  if (t == nb - 1) rowptr[N] = s[t];    // total = E + N
}

__global__ __launch_bounds__(256) void k_scan_final(const int* __restrict__ deg, const int* __restrict__ boff,
                                                    int* __restrict__ rowptr, int* __restrict__ cursor, int N) {
  __shared__ int s[256];
  int t = threadIdx.x;
  int i = blockIdx.x * 256 + t;
  int v = (i < N) ? deg[i] : 0;
  s[t] = v;
  __syncthreads();
  for (int off = 1; off < 256; off <<= 1) {
    int u = (t >= off) ? s[t - off] : 0;
    __syncthreads();
    s[t] += u;
    __syncthreads();
  }
  if (i < N) {
    int ex = boff[blockIdx.x] + s[t] - v;
    rowptr[i] = ex;
    cursor[i] = ex;
  }
}

// XCD-sharded CSR fill: 8 blocks per edge-chunk; block (b&7) ~ one XCD handles
// dst-stripe ((d>>13)&7) -> each XCD's csr writes stay in its own L2 (combine
// to full lines before writeback, killing the 16x write amplification).
__global__ __launch_bounds__(256) void k_fill_shard(const int* __restrict__ ei, int* __restrict__ cursor,
                                                    int* __restrict__ csr, int E, int N, int CH) {
  const int shard = blockIdx.x & 7;
  const int chunk = blockIdx.x >> 3;
  const int i0 = chunk * CH;
  const int i1 = min(i0 + CH, E + N);
  for (int idx = i0 + (int)threadIdx.x; idx < i1; idx += 256) {
    int d = (idx < E) ? ei[E + idx] : idx - E;
    if (((d >> 13) & 7) != shard) continue;
    int s = (idx < E) ? ei[idx] : idx - E;
    int pos = atomicAdd(&cursor[d], 1);
    csr[pos] = s;
  }
}

// ---------------- layer-1 GEMM: split-bf16 MFMA ----------------

// Pack W1^T into per-lane MFMA B fragments (hi/lo split).
__global__ __launch_bounds__(256) void k_prep_b1(const float* __restrict__ W1, __bf16* __restrict__ bhi,
                                                 __bf16* __restrict__ blo) {
  int idx = blockIdx.x * 256 + threadIdx.x;  // 0 .. 16*4*64*8-1 = 32767
  if (idx >= 16 * 4 * 64 * 8) return;
  int e = idx & 7;
  int lane = (idx >> 3) & 63;
  int nf = (idx >> 9) & 3;
  int ks = idx >> 11;
  int k = ks * 32 + (lane >> 4) * 8 + e;
  int col = nf * 16 + (lane & 15);
  float w = (k < 500) ? W1[(size_t)col * 500 + k] : 0.f;
  __bf16 h = (__bf16)w;
  bhi[idx] = h;
  blo[idx] = (__bf16)(w - (float)h);
}

// C[M x 64] = X[M x 500] * W1^T via 3-term split-bf16 MFMA. Also emits bf16 copy of C.
__global__ __launch_bounds__(256) void k_gemm1_mfma(const float* __restrict__ X, const bf16x8* __restrict__ Bhi,
                                                    const bf16x8* __restrict__ Blo, float* __restrict__ out,
                                                    __bf16* __restrict__ outb, int M) {
  const int lane = threadIdx.x & 63;
  const int wid = threadIdx.x >> 6;
  const int row0 = blockIdx.x * 64 + wid * 16;
  const int arow = row0 + (lane & 15);
  const int kgrp = lane >> 4;                 // 0..3
  const bool rowok = arow < M;
  const float* xrow = X + (size_t)arow * 500;

  f32x4 acc[4];
#pragma unroll
  for (int nf = 0; nf < 4; ++nf) acc[nf] = (f32x4){0.f, 0.f, 0.f, 0.f};

#pragma unroll
  for (int ks = 0; ks < 16; ++ks) {
    const int k0 = ks * 32 + kgrp * 8;
    float v[8];
    if (rowok && k0 + 7 < 500) {
      float4 p = *reinterpret_cast<const float4*>(xrow + k0);
      float4 q = *reinterpret_cast<const float4*>(xrow + k0 + 4);
      v[0] = p.x; v[1] = p.y; v[2] = p.z; v[3] = p.w;
      v[4] = q.x; v[5] = q.y; v[6] = q.z; v[7] = q.w;
    } else {
#pragma unroll
      for (int e = 0; e < 8; ++e) v[e] = (rowok && k0 + e < 500) ? xrow[k0 + e] : 0.f;
    }
    bf16x8 ahi, alo;
#pragma unroll
    for (int e = 0; e < 8; ++e) {
      __bf16 h = (__bf16)v[e];
      ahi[e] = h;
      alo[e] = (__bf16)(v[e] - (float)h);
    }
#pragma unroll
    for (int nf = 0; nf < 4; ++nf) {
      bf16x8 bh = Bhi[(ks * 4 + nf) * 64 + lane];
      bf16x8 bl = Blo[(ks * 4 + nf) * 64 + lane];
      acc[nf] = __builtin_amdgcn_mfma_f32_16x16x32_bf16(ahi, bh, acc[nf], 0, 0, 0);
      acc[nf] = __builtin_amdgcn_mfma_f32_16x16x32_bf16(alo, bh, acc[nf], 0, 0, 0);
      acc[nf] = __builtin_amdgcn_mfma_f32_16x16x32_bf16(ahi, bl, acc[nf], 0, 0, 0);
    }
  }

  const int col = lane & 15;
#pragma unroll
  for (int r = 0; r < 4; ++r) {
    int rowd = row0 + (lane >> 4) * 4 + r;
    if (rowd >= M) continue;
#pragma unroll
    for (int nf = 0; nf < 4; ++nf) {
      float fv = acc[nf][r];
      out[(size_t)rowd * 64 + nf * 16 + col] = fv;
      outb[(size_t)rowd * 64 + nf * 16 + col] = (__bf16)fv;
    }
  }
}

// ---------------- dense fp32 GEMM (layer 2) ----------------

__global__ __launch_bounds__(256) void k_transpose_w(const float* __restrict__ W, float* __restrict__ Wt,
                                                     int OUTC, int K, int Kpad) {
  int idx = blockIdx.x * 256 + threadIdx.x;
  int k = idx >> 6, c = idx & 63;
  if (k < Kpad) Wt[k * 64 + c] = (k < K && c < OUTC) ? W[(size_t)c * K + k] : 0.f;
}

template <bool ELU_IN>
__global__ __launch_bounds__(256) void k_gemm(const float* __restrict__ X, const float* __restrict__ Wt,
                                              const float* __restrict__ bias, float* __restrict__ out,
                                              int M, int K, int ldx, int OUTN, int ksteps) {
  __shared__ __align__(16) float xs[32][132];
  __shared__ __align__(16) float ws[32][64];
  const int t = threadIdx.x;
  const int rowg = t >> 4, colg = t & 15;
  const int brow = blockIdx.x * 128;
  float acc[8][4] = {};

  for (int ks = 0; ks < ksteps; ++ks) {
    const int k0 = ks * 32;
#pragma unroll
    for (int i = 0; i < 4; ++i) {
      int f = t + i * 256;
      int r = f >> 3, kq = f & 7;
      int grow = brow + r, gk = k0 + kq * 4;
      float4 v = {0.f, 0.f, 0.f, 0.f};
      if (grow < M && gk < K) {
        v = *reinterpret_cast<const float4*>(X + (size_t)grow * ldx + gk);
        if (ELU_IN) {
          v.x = eluf(v.x + bias[gk + 0]);
          v.y = eluf(v.y + bias[gk + 1]);
          v.z = eluf(v.z + bias[gk + 2]);
          v.w = eluf(v.w + bias[gk + 3]);
        }
      }
      xs[kq * 4 + 0][r] = v.x;
      xs[kq * 4 + 1][r] = v.y;
      xs[kq * 4 + 2][r] = v.z;
      xs[kq * 4 + 3][r] = v.w;
    }
#pragma unroll
    for (int i = 0; i < 2; ++i) {
      int f = t + i * 256;
      int kk = f >> 4, c4 = (f & 15) * 4;
      *reinterpret_cast<float4*>(&ws[kk][c4]) =
          *reinterpret_cast<const float4*>(Wt + (size_t)(k0 + kk) * 64 + c4);
    }
    __syncthreads();
#pragma unroll
    for (int k = 0; k < 32; ++k) {
      float4 xa = *reinterpret_cast<const float4*>(&xs[k][rowg * 8]);
      float4 xb = *reinterpret_cast<const float4*>(&xs[k][rowg * 8 + 4]);
      float4 wv = *reinterpret_cast<const float4*>(&ws[k][colg * 4]);
      float xr[8] = {xa.x, xa.y, xa.z, xa.w, xb.x, xb.y, xb.z, xb.w};
      float wc[4] = {wv.x, wv.y, wv.z, wv.w};
#pragma unroll
      for (int r = 0; r < 8; ++r)
#pragma unroll
        for (int c = 0; c < 4; ++c) acc[r][c] = fmaf(xr[r], wc[c], acc[r][c]);
    }
    __syncthreads();
  }

#pragma unroll
  for (int r = 0; r < 8; ++r) {
    int grow = brow + rowg * 8 + r;
    if (grow >= M) continue;
#pragma unroll
    for (int c = 0; c < 4; ++c) {
      int col = colg * 4 + c;
      if (col < OUTN) out[(size_t)grow * OUTN + col] = acc[r][c];
    }
  }
}

// alpha_s / alpha_d: per (node, head) dot of h[node, head*D..] with att vectors.
template <int D, int F>
__global__ __launch_bounds__(256) void k_alpha(const float* __restrict__ h, const float* __restrict__ a_src,
                                               const float* __restrict__ a_dst, float* __restrict__ as_,
                                               float* __restrict__ ad_, int N) {
  int idx = blockIdx.x * 256 + threadIdx.x;
  int node = idx >> 3, head = idx & 7;
  if (node >= N) return;
  const float* hr = h + (size_t)node * F + head * D;
  float ss = 0.f, sd = 0.f;
#pragma unroll
  for (int d = 0; d < D; ++d) {
    float v = hr[d];
    ss = fmaf(v, a_src[head * D + d], ss);
    sd = fmaf(v, a_dst[head * D + d], sd);
  }
  as_[idx] = ss;
  ad_[idx] = sd;
}

// One wave per dst node, two-pass softmax aggregation. HT = gathered h dtype.
template <int D, int F, typename HT>
__global__ __launch_bounds__(256) void k_agg(const HT* __restrict__ h, const float* __restrict__ as_,
                                             const float* __restrict__ ad_, const int* __restrict__ rowptr,
                                             const int* __restrict__ csr, const float* __restrict__ bias,
                                             float* __restrict__ out, int N) {
  const int lane = threadIdx.x & 63;
  const int n = blockIdx.x * 4 + (threadIdx.x >> 6);
  if (n >= N) return;
  const int r0 = rowptr[n], r1 = rowptr[n + 1];

  // ---- pass 1: per-(node,head) max & denom
  const int h1_ = lane & 7;
  const float ad_h = ad_[(size_t)n * 8 + h1_];
  float m = -1e30f, den = 0.f;
  for (int j = r0 + (lane >> 3); j < r1; j += 8) {
    int s = csr[j];
    float e = lreluf(as_[(size_t)s * 8 + h1_] + ad_h);
    float nm = fmaxf(m, e);
    den = den * __expf(m - nm) + __expf(e - nm);
    m = nm;
  }
#pragma unroll
  for (int off = 8; off < 64; off <<= 1) {
    float mo = __shfl_xor(m, off);
    float dn = __shfl_xor(den, off);
    float nm = fmaxf(m, mo);
    den = den * __expf(m - nm) + dn * __expf(mo - nm);
    m = nm;
  }

  // ---- pass 2: lane = output feature
  const int head = (lane < F) ? (lane / D) : 0;
  const int fidx = (lane < F) ? lane : 0;
  const float m_h = __shfl(m, head);
  const float inv_den = 1.f / __shfl(den, head);
  const float ad_n = __shfl(ad_h, head);

  float acc0 = 0.f, acc1 = 0.f, acc2 = 0.f, acc3 = 0.f;
  int j = r0;
  for (; j + 3 < r1; j += 4) {
    int s0 = csr[j + 0], s1 = csr[j + 1], s2 = csr[j + 2], s3 = csr[j + 3];
    float a0 = as_[(size_t)s0 * 8 + head];
    float a1 = as_[(size_t)s1 * 8 + head];
    float a2 = as_[(size_t)s2 * 8 + head];
    float a3 = as_[(size_t)s3 * 8 + head];
    float v0 = (float)h[(size_t)s0 * F + fidx];
    float v1 = (float)h[(size_t)s1 * F + fidx];
    float v2 = (float)h[(size_t)s2 * F + fidx];
    float v3 = (float)h[(size_t)s3 * F + fidx];
    acc0 = fmaf(__expf(lreluf(a0 + ad_n) - m_h), v0, acc0);
    acc1 = fmaf(__expf(lreluf(a1 + ad_n) - m_h), v1, acc1);
    acc2 = fmaf(__expf(lreluf(a2 + ad_n) - m_h), v2, acc2);
    acc3 = fmaf(__expf(lreluf(a3 + ad_n) - m_h), v3, acc3);
  }
  for (; j < r1; ++j) {
    int s = csr[j];
    float a = as_[(size_t)s * 8 + head];
    float v = (float)h[(size_t)s * F + fidx];
    acc0 = fmaf(__expf(lreluf(a + ad_n) - m_h), v, acc0);
  }
  if (lane < F)
    out[(size_t)n * F + lane] = (acc0 + acc1 + acc2 + acc3) * inv_den + (bias ? bias[lane] : 0.f);
}

// ---------------- launch ----------------

extern "C" void kernel_launch(void* const* d_in, const int* in_sizes, int n_in,
                              void* d_out, int out_size, void* d_ws, size_t ws_size,
                              hipStream_t stream) {
  const float* x    = (const float*)d_in[0];
  const int*   ei   = (const int*)d_in[1];
  const float* W1   = (const float*)d_in[2];
  const float* at_s1 = (const float*)d_in[3];
  const float* at_d1 = (const float*)d_in[4];
  const float* b1   = (const float*)d_in[5];
  const float* W2   = (const float*)d_in[6];
  const float* at_s2 = (const float*)d_in[7];
  const float* at_d2 = (const float*)d_in[8];
  const float* b2   = (const float*)d_in[9];
  float* out = (float*)d_out;

  const int N = in_sizes[0] / 500;
  const int E = in_sizes[1] / 2;

  char* w = (char*)d_ws;
  auto alloc = [&](size_t bytes) -> void* {
    void* p = (void*)w;
    w += (bytes + 255) & ~(size_t)255;
    return p;
  };
  int*   rowptr = (int*)alloc((size_t)(N + 1) * 4);
  int*   cursor = (int*)alloc((size_t)N * 4);
  int*   deg    = (int*)alloc((size_t)N * 4);
  int*   flag   = (int*)alloc(256);
  int*   bsum   = (int*)alloc(4096);
  int*   boff   = (int*)alloc(4096);
  int*   ei_c   = (int*)alloc((size_t)2 * E * 4);
  int*   csr    = (int*)alloc((size_t)(E + N) * 4);
  float* h1     = (float*)alloc((size_t)N * 64 * 4);
  float* o1     = (float*)alloc((size_t)N * 64 * 4);
  float* asb    = (float*)alloc((size_t)N * 8 * 4);
  float* adb    = (float*)alloc((size_t)N * 8 * 4);
  float* Wt2    = (float*)alloc((size_t)64 * 64 * 4);
  __bf16* Bhi1  = (__bf16*)alloc((size_t)32768 * 2);
  __bf16* Blo1  = (__bf16*)alloc((size_t)32768 * 2);
  __bf16* h1b   = (__bf16*)alloc((size_t)N * 64 * 2);

  auto cdiv = [](int a, int b) { return (a + b - 1) / b; };
  const int nbN = cdiv(N, 256);

  // CSR build (shared by both layers: same graph + self-loops)
  k_init<<<nbN, 256, 0, stream>>>(deg, flag, N);
  k_detect<<<cdiv(50000, 256), 256, 0, stream>>>(ei, flag, 50000);
  k_convert<<<cdiv(2 * E, 256), 256, 0, stream>>>(ei, flag, ei_c, 2 * E);
  k_count<<<cdiv(E, 256), 256, 0, stream>>>(ei_c, deg, E);
  k_blocksum<<<nbN, 256, 0, stream>>>(deg, bsum, N);
  k_scan_bsum<<<1, 512, 0, stream>>>(bsum, boff, nbN, rowptr, N);
  k_scan_final<<<nbN, 256, 0, stream>>>(deg, boff, rowptr, cursor, N);
  {
    const int G = 768;
    k_fill_shard<<<8 * G, 256, 0, stream>>>(ei_c, cursor, csr, E, N, cdiv(E + N, G));
  }

  // Layer 1 (split-bf16 MFMA GEMM; also emits bf16 h for the gather)
  k_prep_b1<<<cdiv(32768, 256), 256, 0, stream>>>(W1, Bhi1, Blo1);
  k_gemm1_mfma<<<cdiv(N, 64), 256, 0, stream>>>(x, (const bf16x8*)Bhi1, (const bf16x8*)Blo1, h1, h1b, N);
  k_alpha<8, 64><<<cdiv(N * 8, 256), 256, 0, stream>>>(h1, at_s1, at_d1, asb, adb, N);
  k_agg<8, 64, __bf16><<<cdiv(N, 4), 256, 0, stream>>>(h1b, asb, adb, rowptr, csr, nullptr, o1, N);

  // Layer 2 (bias b1 + ELU fused into GEMM2 input load)
  k_transpose_w<<<cdiv(64 * 64, 256), 256, 0, stream>>>(W2, Wt2, 56, 64, 64);
  k_gemm<true><<<cdiv(N, 128), 256, 0, stream>>>(o1, Wt2, b1, h1, N, 64, 64, 56, 2);
  k_alpha<7, 56><<<cdiv(N * 8, 256), 256, 0, stream>>>(h1, at_s2, at_d2, asb, adb, N);
  k_agg<7, 56, float><<<cdiv(N, 4), 256, 0, stream>>>(h1, asb, adb, rowptr, csr, b2, out, N);
}